// Round 1
// baseline (700.615 us; speedup 1.0000x reference)
//
#include <hip/hip_runtime.h>

typedef unsigned short u16;
typedef __bf16 bf16x8 __attribute__((ext_vector_type(8)));
typedef float f32x4 __attribute__((ext_vector_type(4)));
typedef u16 u16x8 __attribute__((ext_vector_type(8)));

#define NB 4
#define NS 1024
#define ND 1024
#define NH 16
#define NDK 64

__device__ __forceinline__ u16 f2bf(float f) {
    unsigned int u = __float_as_uint(f);
    return (u16)((u + 0x7FFFu + ((u >> 16) & 1u)) >> 16);
}

// ---------------- f32 -> bf16 conversion ----------------
__global__ __launch_bounds__(256) void conv_kernel(const float* __restrict__ src,
                                                   u16* __restrict__ dst) {
    int idx = blockIdx.x * 256 + threadIdx.x;
    const float4* s4 = (const float4*)src + (size_t)idx * 2;
    float4 a = s4[0], c = s4[1];
    u16x8 o;
    o[0] = f2bf(a.x); o[1] = f2bf(a.y); o[2] = f2bf(a.z); o[3] = f2bf(a.w);
    o[4] = f2bf(c.x); o[5] = f2bf(c.y); o[6] = f2bf(c.z); o[7] = f2bf(c.w);
    *((u16x8*)dst + idx) = o;
}

// ---------------- projection GEMM: out = X * W^T + bias (bf16 in/out, f32 acc) ----
// X:[4096][1024], W:[1024][1024] row-major (W[e][d]), out:[4096][1024] bf16
// tile: BM=128, BN=64, BK=64; 4 waves, each wave 32 rows x 64 cols
__global__ __launch_bounds__(256) void proj_kernel(
    const u16* __restrict__ qbf, const u16* __restrict__ kbf,
    const u16* __restrict__ wqbf, const u16* __restrict__ wkbf,
    const float* __restrict__ bq, const float* __restrict__ bk,
    u16* __restrict__ qp, u16* __restrict__ kp) {
    const u16* X = blockIdx.z ? kbf : qbf;
    const u16* W = blockIdx.z ? wkbf : wqbf;
    const float* bias = blockIdx.z ? bk : bq;
    u16* O = blockIdx.z ? kp : qp;

    const int n0 = blockIdx.x * 64;
    const int m0 = blockIdx.y * 128;

    __shared__ u16 Xs[128][72];
    __shared__ u16 Ws[64][72];

    const int t = threadIdx.x;
    const int l = t & 63, w = t >> 6;
    const int lr = l & 15, lh = l >> 4;
    const int wm = w * 32;

    f32x4 zero = {0.f, 0.f, 0.f, 0.f};
    f32x4 acc[2][4];
    for (int mi = 0; mi < 2; mi++)
        for (int nj = 0; nj < 4; nj++) acc[mi][nj] = zero;

    const int sr = t >> 3;            // 0..31
    const int sc8 = (t & 7) * 8;      // 0..56

    for (int k0 = 0; k0 < ND; k0 += 64) {
        // stage X tile 128x64
        for (int p = 0; p < 4; p++) {
            uint4 v = *(const uint4*)(X + (size_t)(m0 + sr + p * 32) * ND + k0 + sc8);
            *(uint4*)&Xs[sr + p * 32][sc8] = v;
        }
        // stage W tile 64x64
        for (int p = 0; p < 2; p++) {
            uint4 v = *(const uint4*)(W + (size_t)(n0 + sr + p * 32) * ND + k0 + sc8);
            *(uint4*)&Ws[sr + p * 32][sc8] = v;
        }
        __syncthreads();
        for (int kk = 0; kk < 2; kk++) {
            const int ko = kk * 32 + lh * 8;
            bf16x8 a[2], bb[4];
            for (int mi = 0; mi < 2; mi++)
                a[mi] = *(const bf16x8*)&Xs[wm + mi * 16 + lr][ko];
            for (int nj = 0; nj < 4; nj++)
                bb[nj] = *(const bf16x8*)&Ws[nj * 16 + lr][ko];
            for (int mi = 0; mi < 2; mi++)
                for (int nj = 0; nj < 4; nj++)
                    acc[mi][nj] = __builtin_amdgcn_mfma_f32_16x16x32_bf16(
                        a[mi], bb[nj], acc[mi][nj], 0, 0, 0);
        }
        __syncthreads();
    }
    // epilogue: C layout col=lane&15, row=(lane>>4)*4+reg
    for (int mi = 0; mi < 2; mi++)
        for (int nj = 0; nj < 4; nj++)
            for (int r = 0; r < 4; r++) {
                int row = m0 + wm + mi * 16 + lh * 4 + r;
                int col = n0 + nj * 16 + lr;
                float v = acc[mi][nj][r] + bias[col];
                O[(size_t)row * ND + col] = f2bf(v);
            }
}

// ---------------- aspect path (pure f32, algebraically folded) ----------------
// aspect_scores[b,h,s] = tanh( v_bh . key[b,s,:] + c0_bh ),
//   v_bh[din] = sum_c aw[b,h,c] * Wk[h*64+c][din]
//   c0_bh    = sum_c aw[b,h,c] * bk[h*64+c] + bias_m
//   aw[b,h,d] = sum_c asp[b,c]*wm[h,c,d],  asp = aspect@Wd^T + bd
__global__ __launch_bounds__(256) void aspect_kernel(
    const float* __restrict__ aspect, const float* __restrict__ Wd,
    const float* __restrict__ bd, const float* __restrict__ wm,
    const float* __restrict__ bm, const float* __restrict__ Wk,
    const float* __restrict__ bk, const float* __restrict__ key,
    float* __restrict__ asps) {
    __shared__ float red[256];
    __shared__ float sAsp[64];
    __shared__ float sAw[64];
    __shared__ float sV[1024];

    const int bid = blockIdx.x;  // ((b*16+h)*4 + sq)
    const int sq = bid & 3, h = (bid >> 2) & 15, b = bid >> 6;
    const int t = threadIdx.x;

    // asp[c] = aspect[b,:] . Wd[c,:] + bd[c]
    {
        int c = t & 63, part = t >> 6;
        const float* ar = aspect + b * ND + part * 256;
        const float* wr = Wd + (size_t)c * ND + part * 256;
        float acc = 0.f;
        for (int i = 0; i < 256; i++) acc += ar[i] * wr[i];
        red[t] = acc;
    }
    __syncthreads();
    if (t < 64) sAsp[t] = red[t] + red[t + 64] + red[t + 128] + red[t + 192] + bd[t];
    __syncthreads();
    // aw[d'] = sum_c asp[c] * wm[h,c,d']
    {
        int dp = t & 63, part = t >> 6;
        float acc = 0.f;
        for (int c = part * 16; c < part * 16 + 16; c++)
            acc += sAsp[c] * wm[((size_t)h * 64 + c) * 64 + dp];
        red[t] = acc;
    }
    __syncthreads();
    if (t < 64) sAw[t] = red[t] + red[t + 64] + red[t + 128] + red[t + 192];
    __syncthreads();
    // v[din] = sum_c aw[c]*Wk[h*64+c][din]; c0 = sum_c aw[c]*bk[h*64+c] + bias_m
    {
        float a0 = 0.f, a1 = 0.f, a2 = 0.f, a3 = 0.f;
        for (int c = 0; c < 64; c++) {
            float aw = sAw[c];
            const float* wkr = Wk + ((size_t)h * 64 + c) * ND;
            a0 += aw * wkr[t];
            a1 += aw * wkr[t + 256];
            a2 += aw * wkr[t + 512];
            a3 += aw * wkr[t + 768];
        }
        sV[t] = a0; sV[t + 256] = a1; sV[t + 512] = a2; sV[t + 768] = a3;
    }
    float c0 = bm[0];
    for (int c = 0; c < 64; c++) c0 += sAw[c] * bk[h * 64 + c];
    __syncthreads();
    // scores for s = sq*256 + t
    const int s = sq * 256 + t;
    const float4* kr = (const float4*)(key + ((size_t)b * NS + s) * ND);
    const float4* vr = (const float4*)sV;
    float acc = 0.f;
    for (int i = 0; i < 256; i++) {
        float4 kv = kr[i], vv = vr[i];
        acc += kv.x * vv.x + kv.y * vv.y + kv.z * vv.z + kv.w * vv.w;
    }
    asps[((size_t)b * NH + h) * NS + s] = tanhf(acc + c0);
}

// ---------------- fused scores + mask + softmax ----------------
// one block = (b, rb, h): 16 q-rows x 1024 k-cols; scores tile in LDS (64 KB f32)
__global__ __launch_bounds__(256) void attn_kernel(
    const u16* __restrict__ qp, const u16* __restrict__ kp,
    const float* __restrict__ asps, const float* __restrict__ shrt,
    const int* __restrict__ maskp, float* __restrict__ out) {
    __shared__ float sc[16][1024];

    const int bid = blockIdx.x;      // b*1024 + rb*16 + h
    const int b = bid >> 10;
    const int rb = (bid >> 4) & 63;
    const int h = bid & 15;
    const int t = threadIdx.x;
    const int l = t & 63, w = t >> 6;
    const int lr = l & 15, lh = l >> 4;

    // A-frags: Q rows rb*16 .. rb*16+15, k = lh*8 .. +7 (+32)
    const u16* qbase = qp + ((size_t)(b * NS + rb * 16 + lr)) * ND + h * 64 + lh * 8;
    bf16x8 a0 = *(const bf16x8*)(qbase);
    bf16x8 a1 = *(const bf16x8*)(qbase + 32);

    f32x4 zero = {0.f, 0.f, 0.f, 0.f};
    // each wave computes col-tiles [w*16, w*16+16)
    for (int i = 0; i < 16; i++) {
        int ct = w * 16 + i;
        const u16* kbase = kp + ((size_t)(b * NS + ct * 16 + lr)) * ND + h * 64 + lh * 8;
        bf16x8 b0 = *(const bf16x8*)(kbase);
        bf16x8 b1 = *(const bf16x8*)(kbase + 32);
        f32x4 acc = zero;
        acc = __builtin_amdgcn_mfma_f32_16x16x32_bf16(a0, b0, acc, 0, 0, 0);
        acc = __builtin_amdgcn_mfma_f32_16x16x32_bf16(a1, b1, acc, 0, 0, 0);
        int col = ct * 16 + lr;
        for (int r = 0; r < 4; r++) sc[lh * 4 + r][col] = acc[r] * 0.125f;
    }
    __syncthreads();

    // phase B: wave w owns rows w*4 .. w*4+3; row-softmax fully in registers
    const size_t bh = (size_t)(b * NH + h);
    const float* arow = asps + bh * NS;
    for (int r4 = 0; r4 < 4; r4++) {
        int row = w * 4 + r4;
        int qrow = rb * 16 + row;
        const float* srow = shrt + (bh * NS + qrow) * NS;
        const int* mrow = maskp + ((size_t)b * NS + qrow) * NS;
        float v[16];
        float m = -3e38f;
        for (int i = 0; i < 16; i++) {
            int c = l + i * 64;
            float s = sc[row][c] + srow[c] + arow[c];
            s = (mrow[c] == 0) ? -1e9f : s;
            v[i] = s;
            m = fmaxf(m, s);
        }
        for (int o = 1; o < 64; o <<= 1) m = fmaxf(m, __shfl_xor(m, o, 64));
        float sum = 0.f;
        for (int i = 0; i < 16; i++) {
            v[i] = __expf(v[i] - m);
            sum += v[i];
        }
        for (int o = 1; o < 64; o <<= 1) sum += __shfl_xor(sum, o, 64);
        float inv = 1.0f / sum;
        float* orow = out + (bh * NS + qrow) * NS;
        for (int i = 0; i < 16; i++) orow[l + i * 64] = v[i] * inv;
    }
}

extern "C" void kernel_launch(void* const* d_in, const int* in_sizes, int n_in,
                              void* d_out, int out_size, void* d_ws, size_t ws_size,
                              hipStream_t stream) {
    const float* query  = (const float*)d_in[0];
    const float* key    = (const float*)d_in[1];
    const int*   maskp  = (const int*)d_in[2];
    const float* aspect = (const float*)d_in[3];
    const float* shrt   = (const float*)d_in[4];
    const float* Wq     = (const float*)d_in[5];
    const float* bq     = (const float*)d_in[6];
    const float* Wk     = (const float*)d_in[7];
    const float* bk     = (const float*)d_in[8];
    const float* Wd     = (const float*)d_in[9];
    const float* bd     = (const float*)d_in[10];
    const float* wm     = (const float*)d_in[11];
    const float* bm     = (const float*)d_in[12];
    float* out = (float*)d_out;

    char* ws = (char*)d_ws;
    const size_t M4 = (size_t)4 * 1024 * 1024;  // 4M elems
    const size_t M1 = (size_t)1024 * 1024;      // 1M elems
    u16* qbf  = (u16*)ws;
    u16* kbf  = qbf + M4;
    u16* wqbf = kbf + M4;
    u16* wkbf = wqbf + M1;
    u16* qp   = wkbf + M1;
    u16* kp   = qp + M4;
    float* asps = (float*)(kp + M4);  // 4*16*1024 f32

    conv_kernel<<<2048, 256, 0, stream>>>(query, qbf);
    conv_kernel<<<2048, 256, 0, stream>>>(key, kbf);
    conv_kernel<<<512, 256, 0, stream>>>(Wq, wqbf);
    conv_kernel<<<512, 256, 0, stream>>>(Wk, wkbf);

    proj_kernel<<<dim3(16, 32, 2), 256, 0, stream>>>(qbf, kbf, wqbf, wkbf, bq, bk, qp, kp);

    aspect_kernel<<<256, 256, 0, stream>>>(aspect, Wd, bd, wm, bm, Wk, bk, key, asps);

    attn_kernel<<<4096, 256, 0, stream>>>(qp, kp, asps, shrt, maskp, out);
}

// Round 2
// 666.108 us; speedup vs baseline: 1.0518x; 1.0518x over previous
//
#include <hip/hip_runtime.h>

typedef unsigned short u16;
typedef __bf16 bf16x8 __attribute__((ext_vector_type(8)));
typedef float f32x4 __attribute__((ext_vector_type(4)));
typedef u16 u16x8 __attribute__((ext_vector_type(8)));

#define NB 4
#define NS 1024
#define ND 1024
#define NH 16
#define NDK 64

__device__ __forceinline__ u16 f2bf(float f) {
    unsigned int u = __float_as_uint(f);
    return (u16)((u + 0x7FFFu + ((u >> 16) & 1u)) >> 16);
}

typedef __attribute__((address_space(3))) unsigned int as3_u32;
typedef __attribute__((address_space(1))) const unsigned int as1_u32;

__device__ __forceinline__ void gload_lds16(const u16* g, u16* lds) {
    __builtin_amdgcn_global_load_lds((as1_u32*)g, (as3_u32*)lds, 16, 0, 0);
}

// ---------------- f32 -> bf16 conversion ----------------
__global__ __launch_bounds__(256) void conv_kernel(const float* __restrict__ src,
                                                   u16* __restrict__ dst) {
    int idx = blockIdx.x * 256 + threadIdx.x;
    const float4* s4 = (const float4*)src + (size_t)idx * 2;
    float4 a = s4[0], c = s4[1];
    u16x8 o;
    o[0] = f2bf(a.x); o[1] = f2bf(a.y); o[2] = f2bf(a.z); o[3] = f2bf(a.w);
    o[4] = f2bf(c.x); o[5] = f2bf(c.y); o[6] = f2bf(c.z); o[7] = f2bf(c.w);
    *((u16x8*)dst + idx) = o;
}

// ---------------- projection GEMM (m97 structure) ----------------
// O = X * W^T + bias; X:[4096][1024] bf16, W:[1024][1024] bf16 (row-major, K contig)
// BM=BN=128, BK=64, 256 threads = 4 waves (2x2), global_load_lds width-16 staging
__global__ __launch_bounds__(256) void proj_kernel(
    const u16* __restrict__ qbf, const u16* __restrict__ kbf,
    const u16* __restrict__ wqbf, const u16* __restrict__ wkbf,
    const float* __restrict__ bq, const float* __restrict__ bk,
    u16* __restrict__ qp, u16* __restrict__ kp) {
    const u16* X = blockIdx.z ? kbf : qbf;
    const u16* W = blockIdx.z ? wkbf : wqbf;
    const float* bias = blockIdx.z ? bk : bq;
    u16* O = blockIdx.z ? kp : qp;

    const int n0 = blockIdx.x * 128;
    const int m0 = blockIdx.y * 128;

    __shared__ u16 As[128 * 64];
    __shared__ u16 Bs[128 * 64];

    const int t = threadIdx.x;
    const int l = t & 63, w = t >> 6;
    const int lr = l & 15, lh = l >> 4;
    const int wr = (w >> 1) * 64, wc = (w & 1) * 64;

    // staging: lane l loads 16B; row = w*8 + p*32 + (l>>3), col = (l&7)*8 u16
    const int srow = w * 8 + (l >> 3);
    const int scol = (l & 7) * 8;

    f32x4 acc[4][4];
    for (int mi = 0; mi < 4; mi++)
        for (int nj = 0; nj < 4; nj++) acc[mi][nj] = (f32x4){0.f, 0.f, 0.f, 0.f};

    for (int k0 = 0; k0 < ND; k0 += 64) {
        for (int p = 0; p < 4; p++) {
            gload_lds16(X + (size_t)(m0 + srow + p * 32) * ND + k0 + scol,
                        As + (w * 8 + p * 32) * 64);
            gload_lds16(W + (size_t)(n0 + srow + p * 32) * ND + k0 + scol,
                        Bs + (w * 8 + p * 32) * 64);
        }
        __syncthreads();
        for (int kk = 0; kk < 2; kk++) {
            const int ko = kk * 32 + lh * 8;
            bf16x8 a[4], b[4];
            for (int mi = 0; mi < 4; mi++)
                a[mi] = *(const bf16x8*)&As[(wr + mi * 16 + lr) * 64 + ko];
            for (int nj = 0; nj < 4; nj++)
                b[nj] = *(const bf16x8*)&Bs[(wc + nj * 16 + lr) * 64 + ko];
            for (int mi = 0; mi < 4; mi++)
                for (int nj = 0; nj < 4; nj++)
                    acc[mi][nj] = __builtin_amdgcn_mfma_f32_16x16x32_bf16(
                        a[mi], b[nj], acc[mi][nj], 0, 0, 0);
        }
        __syncthreads();
    }
    for (int nj = 0; nj < 4; nj++) {
        int col = n0 + wc + nj * 16 + lr;
        float bv = bias[col];
        for (int mi = 0; mi < 4; mi++)
            for (int r = 0; r < 4; r++) {
                int row = m0 + wr + mi * 16 + lh * 4 + r;
                O[(size_t)row * ND + col] = f2bf(acc[mi][nj][r] + bv);
            }
    }
}

// ---------------- aspect precompute: aw, v, c0 per (b,h) ----------------
// v[b,h,din] = sum_c aw[b,h,c]*Wk[h*64+c][din]; c0 = sum_c aw*bk[h*64+c] + bias_m
__global__ __launch_bounds__(256) void aspect_pre(
    const float* __restrict__ aspect, const float* __restrict__ Wd,
    const float* __restrict__ bd, const float* __restrict__ wm,
    const float* __restrict__ bm, const float* __restrict__ Wk,
    const float* __restrict__ bk, float* __restrict__ vout,
    float* __restrict__ c0out) {
    __shared__ float sAsp[64];
    __shared__ float sAw[64];
    const int bid = blockIdx.x;  // b*16 + h
    const int h = bid & 15, b = bid >> 4;
    const int t = threadIdx.x, l = t & 63, w = t >> 6;

    // asp[c] = aspect[b,:].Wd[c,:] + bd[c]; wave w handles c = w*16..w*16+15
    const float4* ar = (const float4*)(aspect + (size_t)b * ND);
    for (int ci = 0; ci < 16; ci++) {
        int c = w * 16 + ci;
        const float4* wr4 = (const float4*)(Wd + (size_t)c * ND);
        float acc = 0.f;
        for (int j = 0; j < 4; j++) {
            float4 av = ar[l + j * 64], wv = wr4[l + j * 64];
            acc += av.x * wv.x + av.y * wv.y + av.z * wv.z + av.w * wv.w;
        }
        for (int o = 1; o < 64; o <<= 1) acc += __shfl_xor(acc, o, 64);
        if (l == 0) sAsp[c] = acc + bd[c];
    }
    __syncthreads();
    if (t < 64) {
        float acc = 0.f;
        for (int c = 0; c < 64; c++)
            acc += sAsp[c] * wm[((size_t)h * 64 + c) * 64 + t];
        sAw[t] = acc;
    }
    __syncthreads();
    {
        float a0 = 0.f, a1 = 0.f, a2 = 0.f, a3 = 0.f;
        for (int c = 0; c < 64; c++) {
            float aw = sAw[c];
            const float* wkr = Wk + ((size_t)h * 64 + c) * ND;
            a0 += aw * wkr[t];
            a1 += aw * wkr[t + 256];
            a2 += aw * wkr[t + 512];
            a3 += aw * wkr[t + 768];
        }
        float* vo = vout + ((size_t)b * NH + h) * ND;
        vo[t] = a0; vo[t + 256] = a1; vo[t + 512] = a2; vo[t + 768] = a3;
    }
    if (t == 0) {
        float c0 = bm[0];
        for (int c = 0; c < 64; c++) c0 += sAw[c] * bk[h * 64 + c];
        c0out[b * NH + h] = c0;
    }
}

// ---------------- aspect scores: tanh(v . key + c0), coalesced ----------------
// block = (b, chunk of 16 s-rows); wave shares key row, 16 h-partials in regs
__global__ __launch_bounds__(256) void aspect_score(
    const float* __restrict__ key, const float* __restrict__ vin,
    const float* __restrict__ c0in, float* __restrict__ asps) {
    __shared__ float vs[16 * 1024];  // 64 KB
    const int bid = blockIdx.x;
    const int chunk = bid & 63, b = bid >> 6;
    const int t = threadIdx.x, l = t & 63, w = t >> 6;

    const float4* vg = (const float4*)(vin + (size_t)b * NH * ND);
    float4* vl = (float4*)vs;
    for (int j = 0; j < 16; j++) vl[t + j * 256] = vg[t + j * 256];
    __syncthreads();

    for (int r = 0; r < 4; r++) {
        int s = chunk * 16 + w * 4 + r;
        const float4* kr = (const float4*)(key + ((size_t)b * NS + s) * ND);
        float4 kx[4];
        for (int j = 0; j < 4; j++) kx[j] = kr[l + j * 64];
        float ph[16];
#pragma unroll
        for (int h = 0; h < 16; h++) {
            const float4* vh = (const float4*)(vs + h * 1024);
            float acc = 0.f;
            for (int j = 0; j < 4; j++) {
                float4 vv = vh[l + j * 64];
                acc += kx[j].x * vv.x + kx[j].y * vv.y + kx[j].z * vv.z + kx[j].w * vv.w;
            }
            ph[h] = acc;
        }
#pragma unroll
        for (int o = 1; o < 64; o <<= 1)
#pragma unroll
            for (int h = 0; h < 16; h++) ph[h] += __shfl_xor(ph[h], o, 64);
        if (l < 16) {
            float val = ph[0];
#pragma unroll
            for (int h = 1; h < 16; h++)
                if (l == h) val = ph[h];
            asps[((size_t)b * NH + l) * NS + s] = tanhf(val + c0in[b * NH + l]);
        }
    }
}

// ---------------- fused scores + mask + softmax ----------------
// block = (b, rb, h): 16 q-rows x 1024 cols; 512 threads, vectorized phase B
__global__ __launch_bounds__(512, 4) void attn_kernel(
    const u16* __restrict__ qp, const u16* __restrict__ kp,
    const float* __restrict__ asps, const float* __restrict__ shrt,
    const int* __restrict__ maskp, float* __restrict__ out) {
    __shared__ float sc[16 * 1024];

    const int bid = blockIdx.x;      // b*1024 + rb*16 + h
    const int b = bid >> 10;
    const int rb = (bid >> 4) & 63;
    const int h = bid & 15;
    const int t = threadIdx.x;
    const int l = t & 63, w = t >> 6;   // w 0..7
    const int lr = l & 15, lh = l >> 4;

    const u16* qbase = qp + ((size_t)(b * NS + rb * 16 + lr)) * ND + h * 64 + lh * 8;
    bf16x8 a0 = *(const bf16x8*)(qbase);
    bf16x8 a1 = *(const bf16x8*)(qbase + 32);

    for (int i = 0; i < 8; i++) {
        int ct = w * 8 + i;
        const u16* kbase = kp + ((size_t)(b * NS + ct * 16 + lr)) * ND + h * 64 + lh * 8;
        bf16x8 b0 = *(const bf16x8*)(kbase);
        bf16x8 b1 = *(const bf16x8*)(kbase + 32);
        f32x4 acc = {0.f, 0.f, 0.f, 0.f};
        acc = __builtin_amdgcn_mfma_f32_16x16x32_bf16(a0, b0, acc, 0, 0, 0);
        acc = __builtin_amdgcn_mfma_f32_16x16x32_bf16(a1, b1, acc, 0, 0, 0);
        int col = ct * 16 + lr;
        for (int r = 0; r < 4; r++) sc[(lh * 4 + r) * 1024 + col] = acc[r] * 0.125f;
    }
    __syncthreads();

    const size_t bh = (size_t)b * NH + h;
    const float4* ar4 = (const float4*)(asps + bh * NS);
    for (int rr = 0; rr < 2; rr++) {
        int row = w * 2 + rr;
        int qrow = rb * 16 + row;
        const float4* srow = (const float4*)(shrt + (bh * NS + qrow) * NS);
        const int4*  mrow = (const int4*)(maskp + ((size_t)b * NS + qrow) * NS);
        const float4* scr = (const float4*)(sc + row * 1024);
        float4 v[4];
        float m = -3e38f;
#pragma unroll
        for (int j = 0; j < 4; j++) {
            int f = l + j * 64;
            float4 s4 = scr[f];
            float4 sh4 = srow[f];
            float4 a4 = ar4[f];
            int4 m4 = mrow[f];
            float4 x;
            x.x = (m4.x == 0) ? -1e9f : s4.x + sh4.x + a4.x;
            x.y = (m4.y == 0) ? -1e9f : s4.y + sh4.y + a4.y;
            x.z = (m4.z == 0) ? -1e9f : s4.z + sh4.z + a4.z;
            x.w = (m4.w == 0) ? -1e9f : s4.w + sh4.w + a4.w;
            v[j] = x;
            m = fmaxf(m, fmaxf(fmaxf(x.x, x.y), fmaxf(x.z, x.w)));
        }
#pragma unroll
        for (int o = 1; o < 64; o <<= 1) m = fmaxf(m, __shfl_xor(m, o, 64));
        float sum = 0.f;
#pragma unroll
        for (int j = 0; j < 4; j++) {
            v[j].x = __expf(v[j].x - m);
            v[j].y = __expf(v[j].y - m);
            v[j].z = __expf(v[j].z - m);
            v[j].w = __expf(v[j].w - m);
            sum += v[j].x + v[j].y + v[j].z + v[j].w;
        }
#pragma unroll
        for (int o = 1; o < 64; o <<= 1) sum += __shfl_xor(sum, o, 64);
        float inv = 1.0f / sum;
        float4* orow = (float4*)(out + (bh * NS + qrow) * NS);
#pragma unroll
        for (int j = 0; j < 4; j++) {
            float4 o4;
            o4.x = v[j].x * inv; o4.y = v[j].y * inv;
            o4.z = v[j].z * inv; o4.w = v[j].w * inv;
            orow[l + j * 64] = o4;
        }
    }
}

extern "C" void kernel_launch(void* const* d_in, const int* in_sizes, int n_in,
                              void* d_out, int out_size, void* d_ws, size_t ws_size,
                              hipStream_t stream) {
    const float* query  = (const float*)d_in[0];
    const float* key    = (const float*)d_in[1];
    const int*   maskp  = (const int*)d_in[2];
    const float* aspect = (const float*)d_in[3];
    const float* shrt   = (const float*)d_in[4];
    const float* Wq     = (const float*)d_in[5];
    const float* bq     = (const float*)d_in[6];
    const float* Wk     = (const float*)d_in[7];
    const float* bk     = (const float*)d_in[8];
    const float* Wd     = (const float*)d_in[9];
    const float* bd     = (const float*)d_in[10];
    const float* wm     = (const float*)d_in[11];
    const float* bm     = (const float*)d_in[12];
    float* out = (float*)d_out;

    char* ws = (char*)d_ws;
    const size_t M4 = (size_t)4 * 1024 * 1024;
    const size_t M1 = (size_t)1024 * 1024;
    u16* qbf  = (u16*)ws;
    u16* kbf  = qbf + M4;
    u16* wqbf = kbf + M4;
    u16* wkbf = wqbf + M1;
    u16* qp   = wkbf + M1;
    u16* kp   = qp + M4;
    float* asps = (float*)(kp + M4);          // 4*16*1024 f32
    float* vbuf = asps + (size_t)NB * NH * NS; // 4*16*1024 f32
    float* c0buf = vbuf + (size_t)NB * NH * ND; // 64 f32

    conv_kernel<<<2048, 256, 0, stream>>>(query, qbf);
    conv_kernel<<<2048, 256, 0, stream>>>(key, kbf);
    conv_kernel<<<512, 256, 0, stream>>>(Wq, wqbf);
    conv_kernel<<<512, 256, 0, stream>>>(Wk, wkbf);

    proj_kernel<<<dim3(8, 32, 2), 256, 0, stream>>>(qbf, kbf, wqbf, wkbf, bq, bk, qp, kp);

    aspect_pre<<<64, 256, 0, stream>>>(aspect, Wd, bd, wm, bm, Wk, bk, vbuf, c0buf);
    aspect_score<<<256, 256, 0, stream>>>(key, vbuf, c0buf, asps);

    attn_kernel<<<4096, 512, 0, stream>>>(qp, kp, asps, shrt, maskp, out);
}